// Round 1
// 189.204 us; speedup vs baseline: 1.0104x; 1.0104x over previous
//
#include <hip/hip_runtime.h>

#define N_NODES 100000
#define N_EDGES 1600000
#define NUM_HEADS 4
#define NEG_SLOPE 0.2f
#define LDSTRIDE 136   // bf16 elems: 272 B rows (68 dwords ≡ 4 mod 32 banks)
#define SEG_BLOCKS 1563   // ceil(400000/256) threads, 4 edges each

typedef __attribute__((ext_vector_type(8))) short bf16x8;
typedef __attribute__((ext_vector_type(4))) float f32x4;

__device__ __forceinline__ unsigned short f2bf(float x) {
    union { float f; unsigned u; } v; v.f = x;
    unsigned r = v.u + 0x7fffu + ((v.u >> 16) & 1u);   // RN-even
    return (unsigned short)(r >> 16);
}
__device__ __forceinline__ float bflo(unsigned v) { return __uint_as_float(v << 16); }
__device__ __forceinline__ float bfhi(unsigned v) { return __uint_as_float(v & 0xffff0000u); }

// ---------------------------------------------------------------------------
// Kernel 0: fused seg + prep (unchanged).
// Blocks [0, SEG_BLOCKS): seg[] from sorted dst, 4 edges/thread via int4.
// Blocks [SEG_BLOCKS, +68): Wt2 (136 x 128 bf16):
//   rows 0..127  : Wt2[n][k] = bf16(W[k][n])
//   rows 128..131: bf16(wl[k][h]);  132..135: bf16(wr[k][h])
// ---------------------------------------------------------------------------
__global__ __launch_bounds__(256) void prep_seg_kernel(
    const int* __restrict__ dst, int* __restrict__ seg,
    const float* __restrict__ W, const float* __restrict__ attn_l,
    const float* __restrict__ attn_r, unsigned short* __restrict__ Wt2)
{
    const int b = blockIdx.x;
    if (b < SEG_BLOCKS) {
        int i4 = b * 256 + threadIdx.x;
        if (i4 >= N_EDGES / 4) return;
        const int e0 = 4 * i4;
        const int4 d = ((const int4*)dst)[i4];
        const int dp = (e0 == 0) ? -1 : dst[e0 - 1];
        for (int n = dp + 1; n <= d.x; ++n) seg[n] = e0;
        for (int n = d.x + 1; n <= d.y; ++n) seg[n] = e0 + 1;
        for (int n = d.y + 1; n <= d.z; ++n) seg[n] = e0 + 2;
        for (int n = d.z + 1; n <= d.w; ++n) seg[n] = e0 + 3;
        if (e0 + 4 == N_EDGES)
            for (int n = d.w + 1; n <= N_NODES; ++n) seg[n] = N_EDGES;
    } else {
        int idx = (b - SEG_BLOCKS) * 256 + threadIdx.x;   // [0, 17408)
        if (idx >= 136 * 128) return;
        int n = idx >> 7, k = idx & 127;
        if (n < 128) {
            Wt2[idx] = f2bf(W[k * 128 + n]);
        } else {
            int h = (n - 128) & 3;
            const float* av = ((n - 128) < 4 ? attn_l : attn_r) + h * 32;
            const float* col = W + k * 128 + h * 32;
            float s = 0.f;
#pragma unroll
            for (int d2 = 0; d2 < 32; ++d2) s += col[d2] * av[d2];
            Wt2[idx] = f2bf(s);
        }
    }
}

// ---------------------------------------------------------------------------
// Kernel 1: [ft | el | er] = bf16(feat) @ Wt2^T via MFMA 16x16x32.
// 64 nodes/block, 256 threads (4 waves); wave w owns rows w*16..+15.
// LDS = B only (37 KB) -> 4 blocks/CU (was 54.4 KB -> 2 blocks/CU).
// A-fragment loaded STRAIGHT from global: lane (quad,l15) needs
// feat[g][ks*32+quad*8 .. +7] (A-frag: m=lane&15, k=quad*8+j) -> 2x float4,
// f2bf in-register. No A_lds staging pass, no pre-MFMA feat barrier work.
// Epilogue: el/er from acc8; ft repacked through B_lds (reused as scratch
// after a barrier) for coalesced int4 stores.
// ---------------------------------------------------------------------------
__global__ __launch_bounds__(256, 4) void gemm_kernel(
    const float* __restrict__ feat, const unsigned short* __restrict__ Wt2,
    unsigned short* __restrict__ ft, float* __restrict__ el,
    float* __restrict__ er)
{
    __shared__ __align__(16) unsigned short B_lds[136 * LDSTRIDE];  // 36992 B
    const int t = threadIdx.x;
    const int nbase = blockIdx.x * 64;

    {   // stage Wt2 (136 rows x 128 k bf16) -> B_lds, coalesced 16B
        const int4* Wt4 = (const int4*)Wt2;
#pragma unroll
        for (int i = 0; i < 9; ++i) {
            int idx = t + 256 * i;            // [0,2304) guard to 2176
            if (idx < 2176) {
                int n = idx >> 4, cg = idx & 15;
                *(int4*)(&B_lds[n * LDSTRIDE + cg * 8]) = Wt4[idx];
            }
        }
    }
    __syncthreads();

    const int w = t >> 6, lane = t & 63;
    const int l15 = lane & 15, quad = lane >> 4;

    int g = nbase + w * 16 + l15;
    if (g >= N_NODES) g = N_NODES - 1;                  // clamped dup rows
    const float4* f4 = (const float4*)feat + (size_t)g * 32 + quad * 2;

    f32x4 acc[9];
#pragma unroll
    for (int c = 0; c < 9; ++c) acc[c] = (f32x4){0.f, 0.f, 0.f, 0.f};

    const unsigned short* Brow = &B_lds[l15 * LDSTRIDE + quad * 8];
    const unsigned short* Brow8 = &B_lds[(128 + (l15 & 7)) * LDSTRIDE + quad * 8];
#pragma unroll
    for (int ks = 0; ks < 4; ++ks) {
        float4 fa = f4[ks * 8];
        float4 fb = f4[ks * 8 + 1];
        bf16x8 a;
        a[0] = (short)f2bf(fa.x); a[1] = (short)f2bf(fa.y);
        a[2] = (short)f2bf(fa.z); a[3] = (short)f2bf(fa.w);
        a[4] = (short)f2bf(fb.x); a[5] = (short)f2bf(fb.y);
        a[6] = (short)f2bf(fb.z); a[7] = (short)f2bf(fb.w);
#pragma unroll
        for (int c = 0; c < 8; ++c) {
            bf16x8 b = *(const bf16x8*)(Brow + (c * 16) * LDSTRIDE + ks * 32);
            acc[c] = __builtin_amdgcn_mfma_f32_16x16x32_bf16(a, b, acc[c], 0, 0, 0);
        }
        bf16x8 b8 = *(const bf16x8*)(Brow8 + ks * 32);
        acc[8] = __builtin_amdgcn_mfma_f32_16x16x32_bf16(a, b8, acc[8], 0, 0, 0);
    }

    // el/er straight from acc8: col l15<4 -> el head l15; l15 in [4,8) -> er
#pragma unroll
    for (int reg = 0; reg < 4; ++reg) {
        const int gg = nbase + w * 16 + quad * 4 + reg;
        if (gg < N_NODES) {
            if (l15 < 4)      el[gg * 4 + l15] = acc[8][reg];
            else if (l15 < 8) er[gg * 4 + (l15 - 4)] = acc[8][reg];
        }
    }

    __syncthreads();   // everyone done reading B_lds -> reuse as ft scratch
#pragma unroll
    for (int c = 0; c < 8; ++c) {
#pragma unroll
        for (int reg = 0; reg < 4; ++reg) {
            B_lds[(w * 16 + quad * 4 + reg) * LDSTRIDE + c * 16 + l15] =
                f2bf(acc[c][reg]);
        }
    }
    __syncthreads();

    // coalesced repack: 64 rows x 128 cols bf16 -> global int4
#pragma unroll
    for (int i = 0; i < 4; ++i) {
        int idx = t + 256 * i;                // [0,1024)
        int node = idx >> 4, cg = idx & 15;
        int gg = nbase + node;
        if (gg < N_NODES) {
            int4 val = *(const int4*)(&B_lds[node * LDSTRIDE + cg * 8]);
            *(int4*)(&ft[(size_t)gg * 128 + cg * 8]) = val;
        }
    }
}

// ---------------------------------------------------------------------------
// Kernel 2: aggregation, non-safe softmax (p = exp(e)), ZERO in-loop shuffles.
// One wave/node. Quarter qt = lane>>4 owns the CONTIGUOUS edge sub-block
// {c0+4qt .. c0+4qt+3}; l15 owns feats 8*l15..+7 (head hf = l15>>2).
// Every lane computes the 4 scores for ITS OWN head locally (x4 redundant
// across the 4 lanes sharing (qt,hf)) -> s, p, denominator all lane-local;
// the old 4 sj-shfl + 16 pj-shfl + 5 d-shfl per iteration are gone.
// Denominator rides the existing quarter-reduce (xor16 + xor32).
// ---------------------------------------------------------------------------
__global__ __launch_bounds__(256) void aggregate_kernel(
    const unsigned short* __restrict__ ft, const float* __restrict__ el,
    const float* __restrict__ er, const int* __restrict__ src,
    const int* __restrict__ seg, float* __restrict__ out)
{
    const int node = blockIdx.x * 4 + (threadIdx.x >> 6);
    if (node >= N_NODES) return;
    const int lane = threadIdx.x & 63;
    const int qt = lane >> 4;         // quarter: edges c0+4qt .. +3
    const int l15 = lane & 15;        // feature group: feats 8*l15..+7
    const int hf = l15 >> 2;          // head of this lane's features/scores

    const int beg = __builtin_amdgcn_readfirstlane(seg[node]);
    const int end = __builtin_amdgcn_readfirstlane(seg[node + 1]);
    const float er_h = er[node * 4 + hf];

    float dpart = 0.f;
    float4 accA = make_float4(0.f, 0.f, 0.f, 0.f);
    float4 accB = make_float4(0.f, 0.f, 0.f, 0.f);

    for (int c0 = beg; c0 < end; c0 += 16) {
        const int cb = c0 + 4 * qt;
        int s4[4];
#pragma unroll
        for (int k = 0; k < 4; ++k) {
            int ci = cb + k;
            s4[k] = src[ci < end ? ci : end - 1];   // clamp (p forced 0)
        }
        float ev[4];
#pragma unroll
        for (int k = 0; k < 4; ++k) ev[k] = el[s4[k] * 4 + hf];
        float p[4];
#pragma unroll
        for (int k = 0; k < 4; ++k) {
            float e = ev[k] + er_h;
            e = (e > 0.f) ? e : NEG_SLOPE * e;
            p[k] = (cb + k < end) ? __expf(e) : 0.f;
            dpart += p[k];
        }
        int4 v[4];
#pragma unroll
        for (int k = 0; k < 4; ++k)
            v[k] = *(const int4*)(ft + (((size_t)(unsigned)s4[k]) << 7) + l15 * 8);
#pragma unroll
        for (int k = 0; k < 4; ++k) {
            const float pj = p[k];
            accA.x += pj * bflo(v[k].x); accA.y += pj * bfhi(v[k].x);
            accA.z += pj * bflo(v[k].y); accA.w += pj * bfhi(v[k].y);
            accB.x += pj * bflo(v[k].z); accB.y += pj * bfhi(v[k].z);
            accB.z += pj * bflo(v[k].w); accB.w += pj * bfhi(v[k].w);
        }
    }

    // reduce across quarters (lanes ^16, ^32); dpart rides along
    dpart  += __shfl_xor(dpart, 16);
    accA.x += __shfl_xor(accA.x, 16); accA.y += __shfl_xor(accA.y, 16);
    accA.z += __shfl_xor(accA.z, 16); accA.w += __shfl_xor(accA.w, 16);
    accB.x += __shfl_xor(accB.x, 16); accB.y += __shfl_xor(accB.y, 16);
    accB.z += __shfl_xor(accB.z, 16); accB.w += __shfl_xor(accB.w, 16);
    dpart  += __shfl_xor(dpart, 32);
    accA.x += __shfl_xor(accA.x, 32); accA.y += __shfl_xor(accA.y, 32);
    accA.z += __shfl_xor(accA.z, 32); accA.w += __shfl_xor(accA.w, 32);
    accB.x += __shfl_xor(accB.x, 32); accB.y += __shfl_xor(accB.y, 32);
    accB.z += __shfl_xor(accB.z, 32); accB.w += __shfl_xor(accB.w, 32);

    const float inv = (dpart > 0.f) ? 1.f / dpart : 0.f; // degree-0 -> zeros

    if (qt == 0) {
        float4 o0 = make_float4(accA.x * inv, accA.y * inv, accA.z * inv, accA.w * inv);
        float4 o1 = make_float4(accB.x * inv, accB.y * inv, accB.z * inv, accB.w * inv);
        float* op = out + (size_t)node * 128 + l15 * 8;
        *(float4*)op = o0;
        *(float4*)(op + 4) = o1;
    }
}

// ---------------------------------------------------------------------------
extern "C" void kernel_launch(void* const* d_in, const int* in_sizes, int n_in,
                              void* d_out, int out_size, void* d_ws, size_t ws_size,
                              hipStream_t stream) {
    const float* feat   = (const float*)d_in[0];
    const int*   src    = (const int*)d_in[1];
    const int*   dst    = (const int*)d_in[2];
    const float* W      = (const float*)d_in[3];
    const float* attn_l = (const float*)d_in[4];
    const float* attn_r = (const float*)d_in[5];
    float* out = (float*)d_out;

    unsigned short* ft = (unsigned short*)d_ws;               // 12.8M bf16
    float* el  = (float*)(ft + (size_t)12800000);
    float* er  = el + 400000;
    unsigned short* Wt2 = (unsigned short*)(er + 400000);     // 136*128 bf16
    int* seg = (int*)(Wt2 + 136 * 128);                       // 100001 int

    prep_seg_kernel<<<SEG_BLOCKS + 68, 256, 0, stream>>>(
        dst, seg, W, attn_l, attn_r, Wt2);
    gemm_kernel<<<(N_NODES + 63) / 64, 256, 0, stream>>>(feat, Wt2, ft, el, er);
    aggregate_kernel<<<(N_NODES + 3) / 4, 256, 0, stream>>>(
        ft, el, er, src, seg, out);
}